// Round 17
// baseline (83.546 us; speedup 1.0000x reference)
//
#include <hip/hip_runtime.h>
#include <hip/hip_bf16.h>
#include <cstddef>

#define B_ 8
#define H_ 12
#define N_ 2048
#define D_ 64
#define M_ 256
#define BH_ (B_*H_)

typedef __attribute__((ext_vector_type(8))) short short8v;
typedef __attribute__((ext_vector_type(4))) float f32x4;

static __device__ __forceinline__ float4 ld4(const float* p){ return *(const float4*)p; }

static __device__ __forceinline__ unsigned short f2bf(float x){
    union { float f; unsigned int u; } v; v.f = x;
    unsigned int r = v.u + 0x7FFFu + ((v.u >> 16) & 1u);
    return (unsigned short)(r >> 16);
}
// HW packed convert: low16 = bf16(a), high16 = bf16(b)  (RNE)
static __device__ __forceinline__ unsigned int pack2(float a, float b){
    unsigned int r;
    asm("v_cvt_pk_bf16_f32 %0, %1, %2" : "=v"(r) : "v"(a), "v"(b));
    return r;
}
// sum two packed-bf16 words elementwise (fp32 add, RNE repack)
static __device__ __forceinline__ unsigned int addbf2(unsigned int a, unsigned int b){
    union { unsigned int u; float f; } alo, ahi, blo, bhi;
    alo.u = a << 16; ahi.u = a & 0xFFFF0000u;
    blo.u = b << 16; bhi.u = b & 0xFFFF0000u;
    return pack2(alo.f + blo.f, ahi.f + bhi.f);
}
static __device__ __forceinline__ uint4 addbf8(uint4 a, uint4 b){
    uint4 r;
    r.x = addbf2(a.x, b.x); r.y = addbf2(a.y, b.y);
    r.z = addbf2(a.z, b.z); r.w = addbf2(a.w, b.w);
    return r;
}

// ---------------- K0: Dct fp32 -> DctA (MFMA frag-linear bf16) + DctT bf16 ----
__global__ __launch_bounds__(256)
void dct_prep_kernel(const float* __restrict__ Dct, unsigned short* __restrict__ DctA,
                     unsigned short* __restrict__ DctT)
{
    __shared__ __align__(16) unsigned short T[64*72];
    const int n0 = blockIdx.x * 64, m0 = blockIdx.y * 64;
    const int tid = threadIdx.x;
    const int mrow = tid >> 2, ng = tid & 3;
    const int m = m0 + mrow;
    unsigned short h[16];
    #pragma unroll
    for (int j = 0; j < 4; ++j) {
        const float4 t = ld4(Dct + (size_t)m*N_ + n0 + ng*16 + j*4);
        h[4*j+0]=f2bf(t.x); h[4*j+1]=f2bf(t.y); h[4*j+2]=f2bf(t.z); h[4*j+3]=f2bf(t.w);
    }
    unsigned int w[8];
    #pragma unroll
    for (int j = 0; j < 8; ++j) w[j] = (unsigned int)h[2*j] | ((unsigned int)h[2*j+1]<<16);
    const int fm = m >> 4;
    #pragma unroll
    for (int s = 0; s < 2; ++s) {
        const int u = 2*ng + s;                   // 0..7
        const int fk = (n0 >> 5) + (u >> 2);
        const int lane = (m & 15) + (u & 3) * 16;
        unsigned short* dst = DctA + ((size_t)(fm*64 + fk)*64 + lane)*8;
        *(uint4*)dst = *(uint4*)&w[s*4];
    }
    #pragma unroll
    for (int j = 0; j < 16; ++j) T[(ng*16+j)*72 + mrow] = h[j];
    __syncthreads();
    const int n = tid >> 2, mg = tid & 3;
    uint4 a  = *(uint4*)&T[n*72 + mg*16];
    uint4 b2 = *(uint4*)&T[n*72 + mg*16 + 8];
    unsigned short* dt = DctT + (size_t)(n0+n)*M_ + m0 + mg*16;
    *(uint4*)dt = a; *(uint4*)(dt+8) = b2;
}

// ---------------- K1: K-split partial GEMM, bf16 partial outputs --------------
// 576 blocks = (panel=(bh,tz), khalf). 256 thr (4 waves, proven group size).
// Each block: FULL 256m x 64d partial over its K=1024 half (BK=128, 8 steps).
// X read once chip-wide (147 MB). A-frags loaded at step-top (before X prefetch
// in the vmcnt FIFO, so MFMA's counted wait never drains X(t+2)). bf16 partials.
__global__ __launch_bounds__(256, 2)
void gemm_qkv(const float* __restrict__ Q, const float* __restrict__ K,
              const float* __restrict__ V, const float* __restrict__ mask,
              const unsigned short* __restrict__ DctA, unsigned short* __restrict__ Part)
{
    __shared__ __align__(16) unsigned short Bsw[2][64*128];  // 2 x 16 KB, row 256 B
    __shared__ __align__(16) float Msk[1024];                // 4 KB: smul*mask (this half)
    const size_t per = (size_t)BH_ * M_ * D_;
    const int wg = blockIdx.x;
    const int id = (wg & 7) * 72 + (wg >> 3);   // 576 = 8 XCD chunks x 72
    const int kh    = id & 1;
    const int panel = id >> 1;                  // 0..287
    const int bh = panel % BH_;
    const int tz = panel / BH_;
    const int b  = bh / H_;
    const float scale = 0.35355339059327373f;
    const float* X; float smul; int um;
    if (tz==0)      { X=Q; smul=scale; um=0; }
    else if (tz==1) { X=K; smul=scale; um=1; }
    else            { X=V; smul=1.0f;  um=1; }
    X += (size_t)bh*N_*D_ + (size_t)kh*1024*D_;
    unsigned short* Y = Part + ((size_t)(tz*2 + kh))*per + (size_t)bh*M_*D_;

    const int tid  = threadIdx.x;
    const int lane = tid & 63, wv = tid >> 6;   // wave wv owns m rows [64wv, 64wv+64)
    const int kq0  = kh*32;                     // fk base for this k-half
    const unsigned short* abase = DctA + (size_t)(wv*4)*32768 + (size_t)lane*8;
    const float* xcol = X + lane;
    const int swz = (lane & 7) << 4;

    f32x4 acc[4][4];
    #pragma unroll
    for (int i = 0; i < 4; ++i)
        #pragma unroll
        for (int j = 0; j < 4; ++j) { acc[i][j].x=0.f; acc[i][j].y=0.f; acc[i][j].z=0.f; acc[i][j].w=0.f; }

    short8v a_[4][4];         // this step's A frags [mf][kh_]
    float xrA[32], xrB[32];

    #define A_LOAD(T) do {                                                    \
        _Pragma("unroll")                                                     \
        for (int mf_ = 0; mf_ < 4; ++mf_)                                     \
            _Pragma("unroll")                                                 \
            for (int j_ = 0; j_ < 4; ++j_)                                    \
                a_[mf_][j_] = *(const short8v*)(abase + (size_t)(mf_*64 + kq0 + 4*(T)+j_)*512); \
    } while(0)

    #define X_LOAD(XR, T) do {                                                \
        const float* xp_ = xcol + (size_t)((T)*128 + wv*32) * D_;             \
        _Pragma("unroll")                                                     \
        for (int i_ = 0; i_ < 32; ++i_) XR[i_] = xp_[(size_t)i_*D_];          \
    } while(0)

    #define WRITE_B(XR, BUF, T) do {                                          \
        const float4* mrow_ = (const float4*)&Msk[(T)*128 + wv*32];           \
        float fmv_[32];                                                       \
        _Pragma("unroll")                                                     \
        for (int j_ = 0; j_ < 8; ++j_) {                                      \
            const float4 t_ = mrow_[j_];                                      \
            fmv_[4*j_]=t_.x; fmv_[4*j_+1]=t_.y; fmv_[4*j_+2]=t_.z; fmv_[4*j_+3]=t_.w; \
        }                                                                     \
        _Pragma("unroll")                                                     \
        for (int c_ = 0; c_ < 4; ++c_) {                                      \
            uint4 w_;                                                         \
            w_.x = pack2(XR[8*c_+0]*fmv_[8*c_+0], XR[8*c_+1]*fmv_[8*c_+1]);   \
            w_.y = pack2(XR[8*c_+2]*fmv_[8*c_+2], XR[8*c_+3]*fmv_[8*c_+3]);   \
            w_.z = pack2(XR[8*c_+4]*fmv_[8*c_+4], XR[8*c_+5]*fmv_[8*c_+5]);   \
            w_.w = pack2(XR[8*c_+6]*fmv_[8*c_+6], XR[8*c_+7]*fmv_[8*c_+7]);   \
            *(uint4*)((char*)&Bsw[BUF][0] + lane*256 + ((wv*64 + c_*16) ^ swz)) = w_; \
        }                                                                     \
    } while(0)

    #define COMPUTE(BUF) do {                                                 \
        _Pragma("unroll")                                                     \
        for (int kh_ = 0; kh_ < 4; ++kh_) {                                   \
            const int colb_ = kh_*64 + (lane>>4)*16;                          \
            _Pragma("unroll")                                                 \
            for (int nf_ = 0; nf_ < 4; ++nf_) {                               \
                const int rr_ = nf_*16 + (lane&15);                           \
                const short8v b_ = *(const short8v*)((char*)&Bsw[BUF][0] + rr_*256 + (colb_ ^ ((rr_&7)<<4))); \
                _Pragma("unroll")                                             \
                for (int mf_ = 0; mf_ < 4; ++mf_)                             \
                    acc[mf_][nf_] = __builtin_amdgcn_mfma_f32_16x16x32_bf16(a_[mf_][kh_], b_, acc[mf_][nf_], 0, 0, 0); \
            }                                                                 \
        }                                                                     \
    } while(0)

    #define BARJ() do { asm volatile("s_waitcnt lgkmcnt(0)" ::: "memory");    \
                        __builtin_amdgcn_sched_barrier(0);                    \
                        __builtin_amdgcn_s_barrier(); } while(0)

    // prologue: mask table (this half) + X(0), X(1)
    {
        const int idx = tid * 4;
        float4 v;
        if (um) {
            v = ld4(mask + (size_t)b*N_ + kh*1024 + idx);
            v.x *= smul; v.y *= smul; v.z *= smul; v.w *= smul;
        } else { v.x = smul; v.y = smul; v.z = smul; v.w = smul; }
        *(float4*)&Msk[idx] = v;
    }
    X_LOAD(xrA, 0);
    X_LOAD(xrB, 1);
    __syncthreads();               // mask table visible (one-time full drain)
    WRITE_B(xrA, 0, 0);
    BARJ();

    // steps t=0..7; A loaded at step top (oldest this step), X(t+2) prefetched
    #define STEP_EVEN(T) do {                                                 \
        A_LOAD(T);                                                            \
        X_LOAD(xrA, (T)+2);                                                   \
        COMPUTE(0);                                                           \
        __builtin_amdgcn_sched_barrier(0);                                    \
        WRITE_B(xrB, 1, (T)+1);                                               \
        BARJ();                                                               \
    } while(0)
    #define STEP_ODD(T) do {                                                  \
        A_LOAD(T);                                                            \
        X_LOAD(xrB, (T)+2);                                                   \
        COMPUTE(1);                                                           \
        __builtin_amdgcn_sched_barrier(0);                                    \
        WRITE_B(xrA, 0, (T)+2);                                               \
        BARJ();                                                               \
    } while(0)
    // NOTE: STEP_ODD(T) writes tile (T)+... careful: see sequencing below.

    // t=0
    A_LOAD(0); X_LOAD(xrA, 2); COMPUTE(0);
    __builtin_amdgcn_sched_barrier(0);
    WRITE_B(xrB, 1, 1); BARJ();
    // t=1
    A_LOAD(1); X_LOAD(xrB, 3); COMPUTE(1);
    __builtin_amdgcn_sched_barrier(0);
    WRITE_B(xrA, 0, 2); BARJ();
    // t=2
    A_LOAD(2); X_LOAD(xrA, 4); COMPUTE(0);
    __builtin_amdgcn_sched_barrier(0);
    WRITE_B(xrB, 1, 3); BARJ();
    // t=3
    A_LOAD(3); X_LOAD(xrB, 5); COMPUTE(1);
    __builtin_amdgcn_sched_barrier(0);
    WRITE_B(xrA, 0, 4); BARJ();
    // t=4
    A_LOAD(4); X_LOAD(xrA, 6); COMPUTE(0);
    __builtin_amdgcn_sched_barrier(0);
    WRITE_B(xrB, 1, 5); BARJ();
    // t=5
    A_LOAD(5); X_LOAD(xrB, 7); COMPUTE(1);
    __builtin_amdgcn_sched_barrier(0);
    WRITE_B(xrA, 0, 6); BARJ();
    // t=6 (no more X to prefetch)
    A_LOAD(6); COMPUTE(0);
    __builtin_amdgcn_sched_barrier(0);
    WRITE_B(xrB, 1, 7); BARJ();
    // t=7
    A_LOAD(7); COMPUTE(1);

    // epilogue: bf16 partial store; m = wv*64 + mf*16 + (lane>>4)*4 + r
    #pragma unroll
    for (int mf = 0; mf < 4; ++mf)
        #pragma unroll
        for (int nf = 0; nf < 4; ++nf)
            #pragma unroll
            for (int r = 0; r < 4; ++r) {
                const int m = wv*64 + mf*16 + (lane>>4)*4 + r;
                const int d = nf*16 + (lane&15);
                Y[(size_t)m*D_ + d] = f2bf(acc[mf][nf][r]);
            }
    #undef A_LOAD
    #undef X_LOAD
    #undef WRITE_B
    #undef COMPUTE
    #undef BARJ
    #undef STEP_EVEN
    #undef STEP_ODD
}

// ---------------- K2: MFMA attention, dual bf16-partial inputs ----------------
__global__ __launch_bounds__(256, 2)
void attn_kernel(const unsigned short* __restrict__ QdA, const unsigned short* __restrict__ QdB,
                 const unsigned short* __restrict__ KdA, const unsigned short* __restrict__ KdB,
                 const unsigned short* __restrict__ VdA, const unsigned short* __restrict__ VdB,
                 unsigned short* __restrict__ CtxT)
{
    __shared__ __align__(16) char LB[65536];
    unsigned short* QA = (unsigned short*)(LB);          // [64][64]  rows 128 B (phase A)
    unsigned short* KB = (unsigned short*)(LB + 8192);   // [256][64] rows 128 B (phase A)
    unsigned short* PL = (unsigned short*)(LB);          // [64][256] rows 512 B (phase B)
    unsigned short* VT = (unsigned short*)(LB + 32768);  // [64][256] rows 512 B (phase B)
    unsigned short* T  = (unsigned short*)(LB);          // [64][72]  (phase C)

    const int mt = blockIdx.x, bh = blockIdx.y;
    const size_t qoff = (size_t)bh*M_*D_ + (size_t)mt*64*D_;
    const size_t koff = (size_t)bh*M_*D_;
    const int tid  = threadIdx.x;
    const int lane = tid & 63, wv = tid >> 6;
    const int l15  = lane & 15, kg = lane >> 4;
    const int swz  = (l15 & 7) << 4;

    // ---- phase A staging: sum dual bf16 partials into swizzled rows
    {
        const int row = tid >> 2, q = tid & 3;
        {
            const uint4 a0 = *(const uint4*)(QdA + qoff + (size_t)row*D_ + q*16);
            const uint4 a1 = *(const uint4*)(QdA + qoff + (size_t)row*D_ + q*16 + 8);
            const uint4 b0 = *(const uint4*)(QdB + qoff + (size_t)row*D_ + q*16);
            const uint4 b1 = *(const uint4*)(QdB + qoff + (size_t)row*D_ + q*16 + 8);
            const uint4 w0 = addbf8(a0, b0);
            const uint4 w1 = addbf8(a1, b1);
            const int s = (row & 7) << 4;
            *(uint4*)((char*)QA + row*128 + ((q*32)      ^ s)) = w0;
            *(uint4*)((char*)QA + row*128 + ((q*32 + 16) ^ s)) = w1;
        }
        #pragma unroll
        for (int c0 = 0; c0 < 4; ++c0) {
            const int krow = c0*64 + row;
            const uint4 a0 = *(const uint4*)(KdA + koff + (size_t)krow*D_ + q*16);
            const uint4 a1 = *(const uint4*)(KdA + koff + (size_t)krow*D_ + q*16 + 8);
            const uint4 b0 = *(const uint4*)(KdB + koff + (size_t)krow*D_ + q*16);
            const uint4 b1 = *(const uint4*)(KdB + koff + (size_t)krow*D_ + q*16 + 8);
            const uint4 w0 = addbf8(a0, b0);
            const uint4 w1 = addbf8(a1, b1);
            const int s = (krow & 7) << 4;
            *(uint4*)((char*)KB + krow*128 + ((q*32)      ^ s)) = w0;
            *(uint4*)((char*)KB + krow*128 + ((q*32 + 16) ^ s)) = w1;
        }
    }
    __syncthreads();

    f32x4 acc[16];
    #pragma unroll
    for (int i = 0; i < 16; ++i) { acc[i].x=0.f; acc[i].y=0.f; acc[i].z=0.f; acc[i].w=0.f; }
    #pragma unroll
    for (int kh = 0; kh < 2; ++kh) {
        const int colb = kh*64 + kg*16;
        const short8v af = *(const short8v*)((char*)QA + (wv*16 + l15)*128 + (colb ^ swz));
        #pragma unroll
        for (int nf = 0; nf < 16; ++nf) {
            const short8v bf = *(const short8v*)((char*)KB + (nf*16 + l15)*128 + (colb ^ swz));
            acc[nf] = __builtin_amdgcn_mfma_f32_16x16x32_bf16(af, bf, acc[nf], 0, 0, 0);
        }
    }

    float inv[4];
    #pragma unroll
    for (int r = 0; r < 4; ++r) {
        float mx = acc[0][r];
        #pragma unroll
        for (int nf = 1; nf < 16; ++nf) mx = fmaxf(mx, acc[nf][r]);
        mx = fmaxf(mx, __shfl_xor(mx, 1));
        mx = fmaxf(mx, __shfl_xor(mx, 2));
        mx = fmaxf(mx, __shfl_xor(mx, 4));
        mx = fmaxf(mx, __shfl_xor(mx, 8));
        float sm = 0.f;
        #pragma unroll
        for (int nf = 0; nf < 16; ++nf) {
            const float p = __expf(acc[nf][r] - mx);
            acc[nf][r] = p; sm += p;
        }
        sm += __shfl_xor(sm, 1);
        sm += __shfl_xor(sm, 2);
        sm += __shfl_xor(sm, 4);
        sm += __shfl_xor(sm, 8);
        inv[r] = 1.0f / sm;
    }
    __syncthreads();

    // ---- phase B staging: P -> PL; summed Vd -> VT transposed
    {
        const int rowbase = wv*16 + kg*4;
        #pragma unroll
        for (int nf = 0; nf < 16; ++nf)
            #pragma unroll
            for (int r = 0; r < 4; ++r) {
                const int rowP = rowbase + r;
                const int byte = rowP*512 + ((((nf*16 + l15)*2)) ^ ((rowP & 7) << 4));
                *(unsigned short*)((char*)PL + byte) = f2bf(acc[nf][r]);
            }
    }
    {
        const int j  = tid & 31;          // d-pair (2j, 2j+1)
        const int kq = tid >> 5;          // k block of 32
        const int d0 = 2*j, d1 = 2*j + 1;
        const int vs0 = (d0 & 7) << 4, vs1 = (d1 & 7) << 4;
        #pragma unroll
        for (int i = 0; i < 32; i += 2) {
            const int k2 = kq*32 + i;
            const unsigned int u0 = addbf2(*(const unsigned int*)(VdA + koff + (size_t)k2*D_ + d0),
                                           *(const unsigned int*)(VdB + koff + (size_t)k2*D_ + d0));
            const unsigned int u1 = addbf2(*(const unsigned int*)(VdA + koff + (size_t)(k2+1)*D_ + d0),
                                           *(const unsigned int*)(VdB + koff + (size_t)(k2+1)*D_ + d0));
            const unsigned int lo = (u0 & 0xFFFFu) | (u1 << 16);
            const unsigned int hi = (u0 >> 16) | (u1 & 0xFFFF0000u);
            *(unsigned int*)((char*)VT + d0*512 + ((k2*2) ^ vs0)) = lo;
            *(unsigned int*)((char*)VT + d1*512 + ((k2*2) ^ vs1)) = hi;
        }
    }
    __syncthreads();

    f32x4 c2[4];
    #pragma unroll
    for (int i = 0; i < 4; ++i) { c2[i].x=0.f; c2[i].y=0.f; c2[i].z=0.f; c2[i].w=0.f; }
    #pragma unroll
    for (int kf = 0; kf < 8; ++kf) {
        const int colb = kf*64 + kg*16;
        const short8v a = *(const short8v*)((char*)PL + (wv*16 + l15)*512 + (colb ^ swz));
        #pragma unroll
        for (int nf2 = 0; nf2 < 4; ++nf2) {
            const int drow = nf2*16 + l15;
            const short8v bb = *(const short8v*)((char*)VT + drow*512 + (colb ^ swz));
            c2[nf2] = __builtin_amdgcn_mfma_f32_16x16x32_bf16(a, bb, c2[nf2], 0, 0, 0);
        }
    }
    __syncthreads();

    {
        const int rowbase = wv*16 + kg*4;
        #pragma unroll
        for (int nf2 = 0; nf2 < 4; ++nf2)
            #pragma unroll
            for (int r = 0; r < 4; ++r) {
                const int d = nf2*16 + l15;
                T[d*72 + rowbase + r] = f2bf(c2[nf2][r] * inv[r]);
            }
    }
    __syncthreads();
    {
        const int d2 = tid >> 2, mg = tid & 3;
        uint4 w0 = *(uint4*)&T[d2*72 + mg*16];
        uint4 w1 = *(uint4*)&T[d2*72 + mg*16 + 8];
        unsigned short* dst = CtxT + (size_t)bh*D_*M_ + (size_t)d2*M_ + mt*64 + mg*16;
        *(uint4*)dst = w0; *(uint4*)(dst+8) = w1;
    }
}

// ---------------- K3: x = DctT @ ctx_t^T, MFMA bf16 ------------------------
__global__ __launch_bounds__(128, 2)
void gemm_out(const unsigned short* __restrict__ DctT, const unsigned short* __restrict__ CtxT,
              float* __restrict__ Out)
{
    __shared__ __align__(16) unsigned short Asw[128*64];
    __shared__ __align__(16) unsigned short Bsw[64*64];
    const int nt = blockIdx.x, bh = blockIdx.y;
    const int n0 = nt*128;
    const unsigned short* ct = CtxT + (size_t)bh*D_*M_;
    float* out = Out + (size_t)bh*N_*D_;
    const int tid = threadIdx.x;
    const int lane = tid & 63, wave = tid >> 6;

    f32x4 acc[4][4];
    #pragma unroll
    for (int i = 0; i < 4; ++i)
        #pragma unroll
        for (int j = 0; j < 4; ++j) { acc[i][j].x=0.f; acc[i][j].y=0.f; acc[i][j].z=0.f; acc[i][j].w=0.f; }

    for (int step = 0; step < 4; ++step) {
        const int k0 = step*64;
        if (step) __syncthreads();
        const int ch = tid & 7;
        #pragma unroll
        for (int rr = 0; rr < 8; ++rr) {
            const int r = (tid>>3) + rr*16;
            const uint4 v = *(const uint4*)(DctT + (size_t)(n0+r)*M_ + k0 + ch*8);
            *(uint4*)((char*)Asw + r*128 + ((ch*16) ^ ((r&7)<<4))) = v;
        }
        #pragma unroll
        for (int rr = 0; rr < 4; ++rr) {
            const int d = (tid>>3) + rr*16;
            const uint4 v = *(const uint4*)(ct + (size_t)d*M_ + k0 + ch*8);
            *(uint4*)((char*)Bsw + d*128 + ((ch*16) ^ (((d>>1)&7)<<4))) = v;
        }
        __syncthreads();
        #pragma unroll
        for (int kh = 0; kh < 2; ++kh) {
            const int colb = kh*64 + (lane>>4)*16;
            short8v a[4], bb[4];
            #pragma unroll
            for (int mf = 0; mf < 4; ++mf) {
                const int r = wave*64 + mf*16 + (lane&15);
                a[mf] = *(const short8v*)((char*)Asw + r*128 + (colb ^ ((r&7)<<4)));
            }
            #pragma unroll
            for (int nf = 0; nf < 4; ++nf) {
                const int r = nf*16 + (lane&15);
                bb[nf] = *(const short8v*)((char*)Bsw + r*128 + (colb ^ (((r>>1)&7)<<4)));
            }
            #pragma unroll
            for (int mf = 0; mf < 4; ++mf)
                #pragma unroll
                for (int nf = 0; nf < 4; ++nf)
                    acc[mf][nf] = __builtin_amdgcn_mfma_f32_16x16x32_bf16(a[mf], bb[nf], acc[mf][nf], 0, 0, 0);
        }
    }
    #pragma unroll
    for (int mf = 0; mf < 4; ++mf)
        #pragma unroll
        for (int nf = 0; nf < 4; ++nf)
            #pragma unroll
            for (int r = 0; r < 4; ++r) {
                const int n = n0 + wave*64 + mf*16 + (lane>>4)*4 + r;
                const int d = nf*16 + (lane&15);
                out[(size_t)n*D_ + d] = acc[mf][nf][r];
            }
}

extern "C" void kernel_launch(void* const* d_in, const int* in_sizes, int n_in,
                              void* d_out, int out_size, void* d_ws, size_t ws_size,
                              hipStream_t stream) {
    const float* Q    = (const float*)d_in[0];
    const float* K    = (const float*)d_in[1];
    const float* V    = (const float*)d_in[2];
    const float* mask = (const float*)d_in[3];
    const float* Dct  = (const float*)d_in[4];
    float* out = (float*)d_out;

    const size_t per = (size_t)BH_ * M_ * D_;   // 1,572,864
    unsigned short* wsu = (unsigned short*)d_ws;
    unsigned short* Part = wsu;                 // 6*per bf16 partials [tz][khalf]
    unsigned short* CtxT = Part + 6*per;
    unsigned short* DctA = CtxT + per;          // 524288 (frag-linear)
    unsigned short* DctT = DctA + (size_t)M_*N_;

    dct_prep_kernel<<<dim3(N_/64, M_/64), 256, 0, stream>>>(Dct, DctA, DctT);
    gemm_qkv<<<dim3(576), 256, 0, stream>>>(Q, K, V, mask, DctA, Part);
    attn_kernel<<<dim3(M_/64, BH_), 256, 0, stream>>>(
        Part + 0*per, Part + 1*per,    // Q partial halves
        Part + 2*per, Part + 3*per,    // K partial halves
        Part + 4*per, Part + 5*per,    // V partial halves
        CtxT);
    gemm_out<<<dim3(N_/128, BH_), 128, 0, stream>>>(DctT, CtxT, out);
}

// Round 18
// 77.929 us; speedup vs baseline: 1.0721x; 1.0721x over previous
//
#include <hip/hip_runtime.h>
#include <hip/hip_bf16.h>
#include <cstddef>

#define B_ 8
#define H_ 12
#define N_ 2048
#define D_ 64
#define M_ 256
#define BH_ (B_*H_)

typedef __attribute__((ext_vector_type(8))) short short8v;
typedef __attribute__((ext_vector_type(4))) float f32x4;

static __device__ __forceinline__ float4 ld4(const float* p){ return *(const float4*)p; }

static __device__ __forceinline__ unsigned short f2bf(float x){
    union { float f; unsigned int u; } v; v.f = x;
    unsigned int r = v.u + 0x7FFFu + ((v.u >> 16) & 1u);
    return (unsigned short)(r >> 16);
}
// HW packed convert: low16 = bf16(a), high16 = bf16(b)  (RNE, same as f2bf)
static __device__ __forceinline__ unsigned int pack2(float a, float b){
    unsigned int r;
    asm("v_cvt_pk_bf16_f32 %0, %1, %2" : "=v"(r) : "v"(a), "v"(b));
    return r;
}

// ---------------- K0: Dct fp32 -> DctA (MFMA frag-linear bf16) + DctT bf16 ----
__global__ __launch_bounds__(256)
void dct_prep_kernel(const float* __restrict__ Dct, unsigned short* __restrict__ DctA,
                     unsigned short* __restrict__ DctT)
{
    __shared__ __align__(16) unsigned short T[64*72];
    const int n0 = blockIdx.x * 64, m0 = blockIdx.y * 64;
    const int tid = threadIdx.x;
    const int mrow = tid >> 2, ng = tid & 3;
    const int m = m0 + mrow;
    unsigned short h[16];
    #pragma unroll
    for (int j = 0; j < 4; ++j) {
        const float4 t = ld4(Dct + (size_t)m*N_ + n0 + ng*16 + j*4);
        h[4*j+0]=f2bf(t.x); h[4*j+1]=f2bf(t.y); h[4*j+2]=f2bf(t.z); h[4*j+3]=f2bf(t.w);
    }
    unsigned int w[8];
    #pragma unroll
    for (int j = 0; j < 8; ++j) w[j] = (unsigned int)h[2*j] | ((unsigned int)h[2*j+1]<<16);
    const int fm = m >> 4;
    #pragma unroll
    for (int s = 0; s < 2; ++s) {
        const int u = 2*ng + s;                   // 0..7
        const int fk = (n0 >> 5) + (u >> 2);
        const int lane = (m & 15) + (u & 3) * 16;
        unsigned short* dst = DctA + ((size_t)(fm*64 + fk)*64 + lane)*8;
        *(uint4*)dst = *(uint4*)&w[s*4];
    }
    #pragma unroll
    for (int j = 0; j < 16; ++j) T[(ng*16+j)*72 + mrow] = h[j];
    __syncthreads();
    const int n = tid >> 2, mg = tid & 3;
    uint4 a  = *(uint4*)&T[n*72 + mg*16];
    uint4 b2 = *(uint4*)&T[n*72 + mg*16 + 8];
    unsigned short* dt = DctT + (size_t)(n0+n)*M_ + m0 + mg*16;
    *(uint4*)dt = a; *(uint4*)(dt+8) = b2;
}

// ---------------- K1: Qd/Kd/Vd = Dct @ (scaled/masked X), MFMA bf16 ----------
// Best-verified config (R16): 576 blocks = (panel,half), 256 thr (4 waves),
// 128m x 64d per block, BK=128 (16 steps), depth-2 A/X register prefetch,
// lgkmcnt-only barrier, XOR-swizzled B LDS, mask via one-time LDS table,
// cvt_pk bf16 packing, bf16 outputs.
__global__ __launch_bounds__(256, 2)
void gemm_qkv(const float* __restrict__ Q, const float* __restrict__ K,
              const float* __restrict__ V, const float* __restrict__ mask,
              const unsigned short* __restrict__ DctA,
              unsigned short* __restrict__ Qb, unsigned short* __restrict__ Kb,
              unsigned short* __restrict__ Vb)
{
    __shared__ __align__(16) unsigned short Bsw[2][64*128];  // 2 x 16 KB, row 256 B
    __shared__ __align__(16) float Msk[N_];                  // 8 KB: smul * mask
    const int wg = blockIdx.x;
    const int id = (wg & 7) * 72 + (wg >> 3);   // 576 = 8 XCD chunks x 72
    const int half  = id & 1;
    const int panel = id >> 1;                  // 0..287
    const int bh = panel % BH_;
    const int tz = panel / BH_;
    const int b  = bh / H_;
    const float scale = 0.35355339059327373f;
    const float* X; unsigned short* Y; float smul; int um;
    if (tz==0)      { X=Q; Y=Qb; smul=scale; um=0; }
    else if (tz==1) { X=K; Y=Kb; smul=scale; um=1; }
    else            { X=V; Y=Vb; smul=1.0f;  um=1; }
    X += (size_t)bh*N_*D_;
    Y += (size_t)bh*M_*D_ + (size_t)half*128*D_;

    const int tid  = threadIdx.x;
    const int lane = tid & 63, wv = tid >> 6;
    const unsigned short* abase = DctA + (size_t)(half*8 + wv*2)*32768 + (size_t)lane*8;
    const float* xcol = X + lane;
    const int swz = (lane & 7) << 4;

    f32x4 acc[2][4];
    #pragma unroll
    for (int i = 0; i < 2; ++i)
        #pragma unroll
        for (int j = 0; j < 4; ++j) { acc[i][j].x=0.f; acc[i][j].y=0.f; acc[i][j].z=0.f; acc[i][j].w=0.f; }

    short8v pa[2][4], pb[2][4];
    float xrA[32], xrB[32];

    #define A_LOAD(P, T) do {                                                 \
        _Pragma("unroll")                                                     \
        for (int mf_ = 0; mf_ < 2; ++mf_)                                     \
            _Pragma("unroll")                                                 \
            for (int kh_ = 0; kh_ < 4; ++kh_)                                 \
                P[mf_][kh_] = *(const short8v*)(abase + (size_t)(mf_*64 + 4*(T)+kh_)*512); \
    } while(0)

    #define X_LOAD(XR, K0) do {                                               \
        const float* xp_ = xcol + (size_t)((K0) + wv*32) * D_;                \
        _Pragma("unroll")                                                     \
        for (int i_ = 0; i_ < 32; ++i_) XR[i_] = xp_[(size_t)i_*D_];          \
    } while(0)

    #define WRITE_B(XR, BUF, K0) do {                                         \
        const float4* mrow_ = (const float4*)&Msk[(K0) + wv*32];              \
        float fmv_[32];                                                       \
        _Pragma("unroll")                                                     \
        for (int j_ = 0; j_ < 8; ++j_) {                                      \
            const float4 t_ = mrow_[j_];                                      \
            fmv_[4*j_]=t_.x; fmv_[4*j_+1]=t_.y; fmv_[4*j_+2]=t_.z; fmv_[4*j_+3]=t_.w; \
        }                                                                     \
        _Pragma("unroll")                                                     \
        for (int c_ = 0; c_ < 4; ++c_) {                                      \
            uint4 w_;                                                         \
            w_.x = pack2(XR[8*c_+0]*fmv_[8*c_+0], XR[8*c_+1]*fmv_[8*c_+1]);   \
            w_.y = pack2(XR[8*c_+2]*fmv_[8*c_+2], XR[8*c_+3]*fmv_[8*c_+3]);   \
            w_.z = pack2(XR[8*c_+4]*fmv_[8*c_+4], XR[8*c_+5]*fmv_[8*c_+5]);   \
            w_.w = pack2(XR[8*c_+6]*fmv_[8*c_+6], XR[8*c_+7]*fmv_[8*c_+7]);   \
            *(uint4*)((char*)&Bsw[BUF][0] + lane*256 + ((wv*64 + c_*16) ^ swz)) = w_; \
        }                                                                     \
    } while(0)

    #define COMPUTE(BUF, P) do {                                              \
        _Pragma("unroll")                                                     \
        for (int kh_ = 0; kh_ < 4; ++kh_) {                                   \
            const int colb_ = kh_*64 + (lane>>4)*16;                          \
            _Pragma("unroll")                                                 \
            for (int nf_ = 0; nf_ < 4; ++nf_) {                               \
                const int rr_ = nf_*16 + (lane&15);                           \
                const short8v b_ = *(const short8v*)((char*)&Bsw[BUF][0] + rr_*256 + (colb_ ^ ((rr_&7)<<4))); \
                _Pragma("unroll")                                             \
                for (int mf_ = 0; mf_ < 2; ++mf_)                             \
                    acc[mf_][nf_] = __builtin_amdgcn_mfma_f32_16x16x32_bf16(P[mf_][kh_], b_, acc[mf_][nf_], 0, 0, 0); \
            }                                                                 \
        }                                                                     \
    } while(0)

    #define BARJ() do { asm volatile("s_waitcnt lgkmcnt(0)" ::: "memory");    \
                        __builtin_amdgcn_sched_barrier(0);                    \
                        __builtin_amdgcn_s_barrier(); } while(0)

    {
        #pragma unroll
        for (int c = 0; c < 2; ++c) {
            const int idx = (tid + c*256) * 4;
            float4 v;
            if (um) {
                v = ld4(mask + (size_t)b*N_ + idx);
                v.x *= smul; v.y *= smul; v.z *= smul; v.w *= smul;
            } else { v.x = smul; v.y = smul; v.z = smul; v.w = smul; }
            *(float4*)&Msk[idx] = v;
        }
    }
    A_LOAD(pa, 0);
    X_LOAD(xrA, 0);
    X_LOAD(xrB, 128);
    __syncthreads();
    WRITE_B(xrA, 0, 0);
    BARJ();

    #define STEP_EVEN(T) do {                                                 \
        A_LOAD(pb, (T)+1);                                                    \
        X_LOAD(xrA, ((T)+2)*128);                                             \
        COMPUTE(0, pa);                                                       \
        __builtin_amdgcn_sched_barrier(0);                                    \
        WRITE_B(xrB, 1, ((T)+1)*128);                                         \
        BARJ();                                                               \
    } while(0)
    #define STEP_ODD(T) do {                                                  \
        A_LOAD(pa, (T)+1);                                                    \
        X_LOAD(xrB, ((T)+2)*128);                                             \
        COMPUTE(1, pb);                                                       \
        __builtin_amdgcn_sched_barrier(0);                                    \
        WRITE_B(xrA, 0, ((T)+1)*128);                                         \
        BARJ();                                                               \
    } while(0)

    for (int tb = 0; tb < 14; tb += 2) {
        STEP_EVEN(tb);
        STEP_ODD(tb+1);
    }
    A_LOAD(pb, 15);
    COMPUTE(0, pa);
    __builtin_amdgcn_sched_barrier(0);
    WRITE_B(xrB, 1, 15*128);
    BARJ();
    COMPUTE(1, pb);

    // epilogue: bf16 store (same RNE rounding K2 applied anyway)
    #pragma unroll
    for (int mf = 0; mf < 2; ++mf)
        #pragma unroll
        for (int nf = 0; nf < 4; ++nf)
            #pragma unroll
            for (int r = 0; r < 4; ++r) {
                const int m = wv*32 + mf*16 + (lane>>4)*4 + r;
                const int d = nf*16 + (lane&15);
                Y[(size_t)m*D_ + d] = f2bf(acc[mf][nf][r]);
            }
    #undef A_LOAD
    #undef X_LOAD
    #undef WRITE_B
    #undef COMPUTE
    #undef BARJ
    #undef STEP_EVEN
    #undef STEP_ODD
}

// ---------------- K2: MFMA attention (bf16 inputs): QK^T -> softmax -> PV ----
__global__ __launch_bounds__(256, 2)
void attn_kernel(const unsigned short* __restrict__ Qd, const unsigned short* __restrict__ Kd,
                 const unsigned short* __restrict__ Vd, unsigned short* __restrict__ CtxT)
{
    __shared__ __align__(16) char LB[65536];
    unsigned short* QA = (unsigned short*)(LB);          // [64][64]  rows 128 B (phase A)
    unsigned short* KB = (unsigned short*)(LB + 8192);   // [256][64] rows 128 B (phase A)
    unsigned short* PL = (unsigned short*)(LB);          // [64][256] rows 512 B (phase B)
    unsigned short* VT = (unsigned short*)(LB + 32768);  // [64][256] rows 512 B (phase B)
    unsigned short* T  = (unsigned short*)(LB);          // [64][72]  (phase C)

    const int mt = blockIdx.x, bh = blockIdx.y;
    const unsigned short* qd = Qd + (size_t)bh*M_*D_ + (size_t)mt*64*D_;
    const unsigned short* kd = Kd + (size_t)bh*M_*D_;
    const unsigned short* vd = Vd + (size_t)bh*M_*D_;
    const int tid  = threadIdx.x;
    const int lane = tid & 63, wv = tid >> 6;
    const int l15  = lane & 15, kg = lane >> 4;
    const int swz  = (l15 & 7) << 4;

    // ---- phase A staging: plain bf16 copies into swizzled rows
    {
        const int row = tid >> 2, q = tid & 3;
        {
            const uint4 w0 = *(const uint4*)(qd + (size_t)row*D_ + q*16);
            const uint4 w1 = *(const uint4*)(qd + (size_t)row*D_ + q*16 + 8);
            const int s = (row & 7) << 4;
            *(uint4*)((char*)QA + row*128 + ((q*32)      ^ s)) = w0;
            *(uint4*)((char*)QA + row*128 + ((q*32 + 16) ^ s)) = w1;
        }
        #pragma unroll
        for (int c0 = 0; c0 < 4; ++c0) {
            const int krow = c0*64 + row;
            const uint4 w0 = *(const uint4*)(kd + (size_t)krow*D_ + q*16);
            const uint4 w1 = *(const uint4*)(kd + (size_t)krow*D_ + q*16 + 8);
            const int s = (krow & 7) << 4;
            *(uint4*)((char*)KB + krow*128 + ((q*32)      ^ s)) = w0;
            *(uint4*)((char*)KB + krow*128 + ((q*32 + 16) ^ s)) = w1;
        }
    }
    __syncthreads();

    f32x4 acc[16];
    #pragma unroll
    for (int i = 0; i < 16; ++i) { acc[i].x=0.f; acc[i].y=0.f; acc[i].z=0.f; acc[i].w=0.f; }
    #pragma unroll
    for (int kh = 0; kh < 2; ++kh) {
        const int colb = kh*64 + kg*16;
        const short8v af = *(const short8v*)((char*)QA + (wv*16 + l15)*128 + (colb ^ swz));
        #pragma unroll
        for (int nf = 0; nf < 16; ++nf) {
            const short8v bf = *(const short8v*)((char*)KB + (nf*16 + l15)*128 + (colb ^ swz));
            acc[nf] = __builtin_amdgcn_mfma_f32_16x16x32_bf16(af, bf, acc[nf], 0, 0, 0);
        }
    }

    float inv[4];
    #pragma unroll
    for (int r = 0; r < 4; ++r) {
        float mx = acc[0][r];
        #pragma unroll
        for (int nf = 1; nf < 16; ++nf) mx = fmaxf(mx, acc[nf][r]);
        mx = fmaxf(mx, __shfl_xor(mx, 1));
        mx = fmaxf(mx, __shfl_xor(mx, 2));
        mx = fmaxf(mx, __shfl_xor(mx, 4));
        mx = fmaxf(mx, __shfl_xor(mx, 8));
        float sm = 0.f;
        #pragma unroll
        for (int nf = 0; nf < 16; ++nf) {
            const float p = __expf(acc[nf][r] - mx);
            acc[nf][r] = p; sm += p;
        }
        sm += __shfl_xor(sm, 1);
        sm += __shfl_xor(sm, 2);
        sm += __shfl_xor(sm, 4);
        sm += __shfl_xor(sm, 8);
        inv[r] = 1.0f / sm;
    }
    __syncthreads();

    // ---- phase B staging: P -> PL (scalar bf16); Vd(bf16) -> VT transposed
    {
        const int rowbase = wv*16 + kg*4;
        #pragma unroll
        for (int nf = 0; nf < 16; ++nf)
            #pragma unroll
            for (int r = 0; r < 4; ++r) {
                const int rowP = rowbase + r;
                const int byte = rowP*512 + ((((nf*16 + l15)*2)) ^ ((rowP & 7) << 4));
                *(unsigned short*)((char*)PL + byte) = f2bf(acc[nf][r]);
            }
    }
    {
        const int j  = tid & 31;          // d-pair (2j, 2j+1)
        const int kq = tid >> 5;          // k block of 32
        const int d0 = 2*j, d1 = 2*j + 1;
        const int vs0 = (d0 & 7) << 4, vs1 = (d1 & 7) << 4;
        #pragma unroll
        for (int i = 0; i < 32; i += 2) {
            const int k2 = kq*32 + i;
            const unsigned int u0 = *(const unsigned int*)(vd + (size_t)k2*D_ + d0);
            const unsigned int u1 = *(const unsigned int*)(vd + (size_t)(k2+1)*D_ + d0);
            const unsigned int lo = (u0 & 0xFFFFu) | (u1 << 16);
            const unsigned int hi = (u0 >> 16) | (u1 & 0xFFFF0000u);
            *(unsigned int*)((char*)VT + d0*512 + ((k2*2) ^ vs0)) = lo;
            *(unsigned int*)((char*)VT + d1*512 + ((k2*2) ^ vs1)) = hi;
        }
    }
    __syncthreads();

    f32x4 c2[4];
    #pragma unroll
    for (int i = 0; i < 4; ++i) { c2[i].x=0.f; c2[i].y=0.f; c2[i].z=0.f; c2[i].w=0.f; }
    #pragma unroll
    for (int kf = 0; kf < 8; ++kf) {
        const int colb = kf*64 + kg*16;
        const short8v a = *(const short8v*)((char*)PL + (wv*16 + l15)*512 + (colb ^ swz));
        #pragma unroll
        for (int nf2 = 0; nf2 < 4; ++nf2) {
            const int drow = nf2*16 + l15;
            const short8v bb = *(const short8v*)((char*)VT + drow*512 + (colb ^ swz));
            c2[nf2] = __builtin_amdgcn_mfma_f32_16x16x32_bf16(a, bb, c2[nf2], 0, 0, 0);
        }
    }
    __syncthreads();

    {
        const int rowbase = wv*16 + kg*4;
        #pragma unroll
        for (int nf2 = 0; nf2 < 4; ++nf2)
            #pragma unroll
            for (int r = 0; r < 4; ++r) {
                const int d = nf2*16 + l15;
                T[d*72 + rowbase + r] = f2bf(c2[nf2][r] * inv[r]);
            }
    }
    __syncthreads();
    {
        const int d2 = tid >> 2, mg = tid & 3;
        uint4 w0 = *(uint4*)&T[d2*72 + mg*16];
        uint4 w1 = *(uint4*)&T[d2*72 + mg*16 + 8];
        unsigned short* dst = CtxT + (size_t)bh*D_*M_ + (size_t)d2*M_ + mt*64 + mg*16;
        *(uint4*)dst = w0; *(uint4*)(dst+8) = w1;
    }
}

// ---------------- K3: x = DctT @ ctx_t^T, MFMA bf16 ------------------------
__global__ __launch_bounds__(128, 2)
void gemm_out(const unsigned short* __restrict__ DctT, const unsigned short* __restrict__ CtxT,
              float* __restrict__ Out)
{
    __shared__ __align__(16) unsigned short Asw[128*64];
    __shared__ __align__(16) unsigned short Bsw[64*64];
    const int nt = blockIdx.x, bh = blockIdx.y;
    const int n0 = nt*128;
    const unsigned short* ct = CtxT + (size_t)bh*D_*M_;
    float* out = Out + (size_t)bh*N_*D_;
    const int tid = threadIdx.x;
    const int lane = tid & 63, wave = tid >> 6;

    f32x4 acc[4][4];
    #pragma unroll
    for (int i = 0; i < 4; ++i)
        #pragma unroll
        for (int j = 0; j < 4; ++j) { acc[i][j].x=0.f; acc[i][j].y=0.f; acc[i][j].z=0.f; acc[i][j].w=0.f; }

    for (int step = 0; step < 4; ++step) {
        const int k0 = step*64;
        if (step) __syncthreads();
        const int ch = tid & 7;
        #pragma unroll
        for (int rr = 0; rr < 8; ++rr) {
            const int r = (tid>>3) + rr*16;
            const uint4 v = *(const uint4*)(DctT + (size_t)(n0+r)*M_ + k0 + ch*8);
            *(uint4*)((char*)Asw + r*128 + ((ch*16) ^ ((r&7)<<4))) = v;
        }
        #pragma unroll
        for (int rr = 0; rr < 4; ++rr) {
            const int d = (tid>>3) + rr*16;
            const uint4 v = *(const uint4*)(ct + (size_t)d*M_ + k0 + ch*8);
            *(uint4*)((char*)Bsw + d*128 + ((ch*16) ^ (((d>>1)&7)<<4))) = v;
        }
        __syncthreads();
        #pragma unroll
        for (int kh = 0; kh < 2; ++kh) {
            const int colb = kh*64 + (lane>>4)*16;
            short8v a[4], bb[4];
            #pragma unroll
            for (int mf = 0; mf < 4; ++mf) {
                const int r = wave*64 + mf*16 + (lane&15);
                a[mf] = *(const short8v*)((char*)Asw + r*128 + (colb ^ ((r&7)<<4)));
            }
            #pragma unroll
            for (int nf = 0; nf < 4; ++nf) {
                const int r = nf*16 + (lane&15);
                bb[nf] = *(const short8v*)((char*)Bsw + r*128 + (colb ^ (((r>>1)&7)<<4)));
            }
            #pragma unroll
            for (int mf = 0; mf < 4; ++mf)
                #pragma unroll
                for (int nf = 0; nf < 4; ++nf)
                    acc[mf][nf] = __builtin_amdgcn_mfma_f32_16x16x32_bf16(a[mf], bb[nf], acc[mf][nf], 0, 0, 0);
        }
    }
    #pragma unroll
    for (int mf = 0; mf < 4; ++mf)
        #pragma unroll
        for (int nf = 0; nf < 4; ++nf)
            #pragma unroll
            for (int r = 0; r < 4; ++r) {
                const int n = n0 + wave*64 + mf*16 + (lane>>4)*4 + r;
                const int d = nf*16 + (lane&15);
                out[(size_t)n*D_ + d] = acc[mf][nf][r];
            }
}

extern "C" void kernel_launch(void* const* d_in, const int* in_sizes, int n_in,
                              void* d_out, int out_size, void* d_ws, size_t ws_size,
                              hipStream_t stream) {
    const float* Q    = (const float*)d_in[0];
    const float* K    = (const float*)d_in[1];
    const float* V    = (const float*)d_in[2];
    const float* mask = (const float*)d_in[3];
    const float* Dct  = (const float*)d_in[4];
    float* out = (float*)d_out;

    const size_t per = (size_t)BH_ * M_ * D_;          // 1,572,864
    unsigned short* wsu = (unsigned short*)d_ws;
    unsigned short* Qb   = wsu;                        // bf16 Qd
    unsigned short* Kb   = Qb + per;                   // bf16 Kd
    unsigned short* Vb   = Kb + per;                   // bf16 Vd
    unsigned short* CtxT = Vb + per;
    unsigned short* DctA = CtxT + per;                 // 524288 (frag-linear)
    unsigned short* DctT = DctA + (size_t)M_ * N_;     // 524288

    dct_prep_kernel<<<dim3(N_/64, M_/64), 256, 0, stream>>>(Dct, DctA, DctT);
    gemm_qkv<<<dim3(576), 256, 0, stream>>>(Q, K, V, mask, DctA, Qb, Kb, Vb);
    attn_kernel<<<dim3(M_/64, BH_), 256, 0, stream>>>(Qb, Kb, Vb, CtxT);
    gemm_out<<<dim3(N_/128, BH_), 128, 0, stream>>>(DctT, CtxT, out);
}